// Round 10
// baseline (1571.063 us; speedup 1.0000x reference)
//
#include <hip/hip_runtime.h>
#include <math.h>

typedef unsigned int u32;
typedef unsigned short u16;

#define NS 128          // T-1 timesteps
#define A_ 5
#define B_ 128
#define NTH 256
#define BC 16
#define NWG 40          // 5 agents x 8 chunks of 16 rows
#define LOG2PI_F 1.8378770664093453f

// ---- B-fragment packed weight layout (u16 units), per agent ----
// frag order: [layer][ntile][kstep][lane 0..63][j 0..7], elem = W[k][n] with
// k = kstep*32 + (lane>>4)*8 + j, n = ntile*16 + (lane&15).
#define OF_E1 0         // 8 ntiles x 5 ksteps
#define OF_P1 20480
#define OF_D1 40960
#define OF_G  61440     // 24 ntiles x 5
#define OF_E2 122880    // 8 x 4
#define OF_P2 139264
#define OF_D2 155648
#define OF_H  172032    // 4 heads x (1 x 4)
#define OF_DH 180224    // 1 x 4 (cols: dm0 dm1 ds0 ds1, rest 0)
#define AGE   182272

typedef _Float16 f16x8 __attribute__((ext_vector_type(8)));
typedef float f32x4 __attribute__((ext_vector_type(4)));

__device__ __forceinline__ u16 f2h(float f) { _Float16 h = (_Float16)f; return __builtin_bit_cast(u16, h); }
__device__ __forceinline__ float h2f(u16 u) { return (float)__builtin_bit_cast(_Float16, u); }
__device__ __forceinline__ float softplusf_(float x) { return fmaxf(x, 0.f) + log1pf(expf(-fabsf(x))); }
__device__ __forceinline__ float sigmoidf_(float x) { return 1.f / (1.f + expf(-x)); }

#define MFMA16(af, bf, acc) __builtin_amdgcn_mfma_f32_16x16x32_f16((af), (bf), (acc), 0, 0, 0)

#define UST 168   // Uf row stride (elems): 336B -> 2-way max on frag reads
#define AST 136   // activation row stride: 272B -> 2-way max

struct PM {
    const float* __restrict__ y;
    const float* __restrict__ eps;
    const float* __restrict__ eb1; const float* __restrict__ eb2;
    const float* __restrict__ pb1; const float* __restrict__ pb2;
    const float* __restrict__ db1; const float* __restrict__ db2;
    const float* __restrict__ emb; const float* __restrict__ esb;
    const float* __restrict__ pmb; const float* __restrict__ psb;
    const float* __restrict__ dmb; const float* __restrict__ dsb;
    const float* __restrict__ bih; const float* __restrict__ bhh;
    const u16* __restrict__ wq;
    float* __restrict__ partials;
};

__global__ void __launch_bounds__(NTH, 1) vrnn10(PM p) {
    const int tid = threadIdx.x;
    const int wave = tid >> 6;               // 0..3
    const int lane = tid & 63;
    const int ln = lane & 15;                // fragment row/col index
    const int lq = lane >> 4;                // k-quad / row-quad
    const int a = blockIdx.x >> 3;
    const int b0 = (blockIdx.x & 7) * BC;

    __shared__ __align__(16) u16 Uf[16 * UST];       // [x2 y10 z16 pad4 h128 pad8]
    __shared__ __align__(16) u16 aAf[16 * AST], aBf[16 * AST], aCf[16 * AST], aDf[16 * AST];
    __shared__ float mueL[16][17], sdeL[16][17], mupL[16][17], sdpL[16][17];
    __shared__ float xf[16][2], dmuL[16][2], dsdL[16][2];
    __shared__ float bE1L[128], bP1L[128], bD1L[128];
    __shared__ float bE2L[128], bP2L[128], bD2L[128];
    __shared__ float bIHL[384], bHHL[384], bHl[64], bDHl[4];
    __shared__ float red[NTH];

    const f16x8* __restrict__ W8 = (const f16x8*)p.wq + (size_t)a * (AGE / 8);

    // ---- init ----
    for (int i = tid; i < 16 * UST; i += NTH) Uf[i] = 0;
    if (tid < 128) {
        bE1L[tid] = p.eb1[a * 128 + tid]; bE2L[tid] = p.eb2[a * 128 + tid];
        bP1L[tid] = p.pb1[a * 128 + tid]; bP2L[tid] = p.pb2[a * 128 + tid];
        bD1L[tid] = p.db1[a * 128 + tid]; bD2L[tid] = p.db2[a * 128 + tid];
    }
    for (int i = tid; i < 384; i += NTH) {
        bIHL[i] = p.bih[a * 384 + i]; bHHL[i] = p.bhh[a * 384 + i];
    }
    if (tid < 64) {
        int h = tid >> 4, c = tid & 15;
        bHl[tid] = ((h == 0) ? p.emb : (h == 1) ? p.esb : (h == 2) ? p.pmb : p.psb)[a * 16 + c];
    }
    if (tid < 4) bDHl[tid] = (tid < 2) ? p.dmb[a * 2 + tid] : p.dsb[a * 2 + (tid - 2)];

    // ---- prefetch t=0 inputs ----
    const int ry = tid / 10, jy = tid - ry * 10;            // tid<160
    const int rx = (tid - 160) >> 1, xdx = (tid - 160) & 1; // 160<=tid<192
    const int re = tid >> 4, ze = tid & 15;                 // all 256
    float ypre = 0.f, xpre = 0.f;
    if (tid < 160) ypre = p.y[0 * (B_ * 10) + (b0 + ry) * 10 + jy];
    else if (tid < 192) xpre = p.y[1 * (B_ * 10) + (b0 + rx) * 10 + a * 2 + xdx];
    float epre = p.eps[(((size_t)0 * A_ + a) * B_ + (b0 + re)) * 16 + ze];

    float kl_acc = 0.f, nll_acc = 0.f;

#pragma unroll 1
    for (int t = 0; t < NS; ++t) {
        const int tn = (t + 1 < NS) ? t + 1 : t;
        __syncthreads();
        // ---- P1: commit inputs, prefetch next ----
        if (tid < 160) {
            Uf[ry * UST + 2 + jy] = f2h(ypre);
            ypre = p.y[tn * (B_ * 10) + (b0 + ry) * 10 + jy];
        } else if (tid < 192) {
            Uf[rx * UST + xdx] = f2h(xpre); xf[rx][xdx] = xpre;
            xpre = p.y[(tn + 1) * (B_ * 10) + (b0 + rx) * 10 + a * 2 + xdx];
        }
        __syncthreads();

        // ---- P2: enc1 + pri1  [16x160]x[160x128] ----
        {
            f32x4 accE[2] = {{0,0,0,0},{0,0,0,0}}, accP[2] = {{0,0,0,0},{0,0,0,0}};
#pragma unroll
            for (int k = 0; k < 5; ++k) {
                f16x8 af = *(const f16x8*)(Uf + ln * UST + k * 32 + lq * 8);
#pragma unroll
                for (int i = 0; i < 2; ++i) {
                    int tg = 2 * wave + i;
                    f16x8 b1 = W8[OF_E1 / 8 + (tg * 5 + k) * 64 + lane];
                    accE[i] = MFMA16(af, b1, accE[i]);
                    f16x8 b2 = W8[OF_P1 / 8 + (tg * 5 + k) * 64 + lane];
                    accP[i] = MFMA16(af, b2, accP[i]);
                }
            }
#pragma unroll
            for (int i = 0; i < 2; ++i) {
                int c = (2 * wave + i) * 16 + ln;
                float bE = bE1L[c], bP = bP1L[c];
#pragma unroll
                for (int j = 0; j < 4; ++j) {
                    int row = lq * 4 + j;
                    aAf[row * AST + c] = f2h(fmaxf(accE[i][j] + bE, 0.f));
                    aCf[row * AST + c] = f2h(fmaxf(accP[i][j] + bP, 0.f));
                }
            }
        }
        __syncthreads();

        // ---- P3: enc2 (aAf->aBf), pri2 (aCf->aDf)  [16x128]x[128x128] ----
        {
            f32x4 accE[2] = {{0,0,0,0},{0,0,0,0}}, accP[2] = {{0,0,0,0},{0,0,0,0}};
#pragma unroll
            for (int k = 0; k < 4; ++k) {
                f16x8 a1 = *(const f16x8*)(aAf + ln * AST + k * 32 + lq * 8);
                f16x8 a2 = *(const f16x8*)(aCf + ln * AST + k * 32 + lq * 8);
#pragma unroll
                for (int i = 0; i < 2; ++i) {
                    int tg = 2 * wave + i;
                    f16x8 b1 = W8[OF_E2 / 8 + (tg * 4 + k) * 64 + lane];
                    accE[i] = MFMA16(a1, b1, accE[i]);
                    f16x8 b2 = W8[OF_P2 / 8 + (tg * 4 + k) * 64 + lane];
                    accP[i] = MFMA16(a2, b2, accP[i]);
                }
            }
#pragma unroll
            for (int i = 0; i < 2; ++i) {
                int c = (2 * wave + i) * 16 + ln;
                float bE = bE2L[c], bP = bP2L[c];
#pragma unroll
                for (int j = 0; j < 4; ++j) {
                    int row = lq * 4 + j;
                    aBf[row * AST + c] = f2h(fmaxf(accE[i][j] + bE, 0.f));
                    aDf[row * AST + c] = f2h(fmaxf(accP[i][j] + bP, 0.f));
                }
            }
        }
        __syncthreads();

        // ---- P4: 4 gaussian heads (wave = head)  [16x128]x[128x16] ----
        {
            const u16* src = (wave < 2) ? aBf : aDf;
            f32x4 acc = {0,0,0,0};
#pragma unroll
            for (int k = 0; k < 4; ++k) {
                f16x8 af = *(const f16x8*)(src + ln * AST + k * 32 + lq * 8);
                f16x8 bf = W8[OF_H / 8 + wave * 256 + k * 64 + lane];
                acc = MFMA16(af, bf, acc);
            }
            float bb = bHl[wave * 16 + ln];
#pragma unroll
            for (int j = 0; j < 4; ++j) {
                int row = lq * 4 + j;
                float v = acc[j] + bb;
                if (wave == 0)      mueL[row][ln] = v;
                else if (wave == 1) sdeL[row][ln] = softplusf_(v);
                else if (wave == 2) mupL[row][ln] = v;
                else                sdpL[row][ln] = softplusf_(v);
            }
        }
        __syncthreads();

        // ---- P5: z sample + KL (16 rows x 16 zd = 256 threads) ----
        {
            float em = mueL[re][ze], es = sdeL[re][ze], pm = mupL[re][ze], ps = sdpL[re][ze];
            float zv = fmaf(epre, es, em);
            Uf[re * UST + 12 + ze] = f2h(zv);
            float dm = em - pm;
            kl_acc += 0.5f * (2.f * (logf(ps) - logf(es)) + (es * es + dm * dm) / (ps * ps) - 1.f);
            epre = p.eps[(((size_t)tn * A_ + a) * B_ + (b0 + re)) * 16 + ze];
        }
        __syncthreads();

        // ---- P6: dec1 + GRU (kstep 0 = [x,z] region -> gate2 ih split) ----
        float hn[2][4];
        {
            f32x4 aO[2]  = {{0,0,0,0},{0,0,0,0}};
            f32x4 g0a[2] = {{0,0,0,0},{0,0,0,0}};
            f32x4 g1a[2] = {{0,0,0,0},{0,0,0,0}};
            f32x4 g2i[2] = {{0,0,0,0},{0,0,0,0}};
            f32x4 g2h[2] = {{0,0,0,0},{0,0,0,0}};
#pragma unroll
            for (int k = 0; k < 5; ++k) {
                f16x8 af = *(const f16x8*)(Uf + ln * UST + k * 32 + lq * 8);
#pragma unroll
                for (int i = 0; i < 2; ++i) {
                    int tg = 2 * wave + i;
                    f16x8 bD = W8[OF_D1 / 8 + (tg * 5 + k) * 64 + lane];
                    aO[i] = MFMA16(af, bD, aO[i]);
                    f16x8 b0 = W8[OF_G / 8 + ((0 + tg) * 5 + k) * 64 + lane];
                    g0a[i] = MFMA16(af, b0, g0a[i]);
                    f16x8 b1 = W8[OF_G / 8 + ((8 + tg) * 5 + k) * 64 + lane];
                    g1a[i] = MFMA16(af, b1, g1a[i]);
                    f16x8 b2 = W8[OF_G / 8 + ((16 + tg) * 5 + k) * 64 + lane];
                    if (k == 0) g2i[i] = MFMA16(af, b2, g2i[i]);
                    else        g2h[i] = MFMA16(af, b2, g2h[i]);
                }
            }
#pragma unroll
            for (int i = 0; i < 2; ++i) {
                int c = (2 * wave + i) * 16 + ln;
                float bD = bD1L[c];
                float br = bIHL[c] + bHHL[c];
                float bz = bIHL[128 + c] + bHHL[128 + c];
                float bgi = bIHL[256 + c], bgh = bHHL[256 + c];
#pragma unroll
                for (int j = 0; j < 4; ++j) {
                    int row = lq * 4 + j;
                    aAf[row * AST + c] = f2h(fmaxf(aO[i][j] + bD, 0.f));
                    float rr = sigmoidf_(g0a[i][j] + br);
                    float zz = sigmoidf_(g1a[i][j] + bz);
                    float nn = tanhf(fmaf(rr, g2h[i][j] + bgh, g2i[i][j] + bgi));
                    float hold = h2f(Uf[row * UST + 32 + c]);
                    hn[i][j] = fmaf(zz, hold - nn, nn);
                }
            }
        }
        __syncthreads();

        // ---- P7: h write + dec2 (aAf -> aBf) ----
#pragma unroll
        for (int i = 0; i < 2; ++i) {
            int c = (2 * wave + i) * 16 + ln;
#pragma unroll
            for (int j = 0; j < 4; ++j)
                Uf[(lq * 4 + j) * UST + 32 + c] = f2h(hn[i][j]);
        }
        {
            f32x4 acc[2] = {{0,0,0,0},{0,0,0,0}};
#pragma unroll
            for (int k = 0; k < 4; ++k) {
                f16x8 af = *(const f16x8*)(aAf + ln * AST + k * 32 + lq * 8);
#pragma unroll
                for (int i = 0; i < 2; ++i) {
                    int tg = 2 * wave + i;
                    f16x8 bf = W8[OF_D2 / 8 + (tg * 4 + k) * 64 + lane];
                    acc[i] = MFMA16(af, bf, acc[i]);
                }
            }
#pragma unroll
            for (int i = 0; i < 2; ++i) {
                int c = (2 * wave + i) * 16 + ln;
                float bE = bD2L[c];
#pragma unroll
                for (int j = 0; j < 4; ++j)
                    aBf[(lq * 4 + j) * AST + c] = f2h(fmaxf(acc[i][j] + bE, 0.f));
            }
        }
        __syncthreads();

        // ---- P8: dec heads (wave 0): [16x128]x[128x4] ----
        if (wave == 0) {
            f32x4 acc = {0,0,0,0};
#pragma unroll
            for (int k = 0; k < 4; ++k) {
                f16x8 af = *(const f16x8*)(aBf + ln * AST + k * 32 + lq * 8);
                f16x8 bf = W8[OF_DH / 8 + k * 64 + lane];
                acc = MFMA16(af, bf, acc);
            }
            if (ln < 4) {
                float bb = bDHl[ln];
#pragma unroll
                for (int j = 0; j < 4; ++j) {
                    int row = lq * 4 + j;
                    float v = acc[j] + bb;
                    if (ln < 2) dmuL[row][ln] = v;
                    else        dsdL[row][ln - 2] = softplusf_(v);
                }
            }
        }
        __syncthreads();

        // ---- P9: NLL (16 rows x 2 dims) ----
        if (tid < 32) {
            int r = tid >> 1, xd = tid & 1;
            float d = xf[r][xd] - dmuL[r][xd];
            float sd = dsdL[r][xd];
            nll_acc += 0.5f * (d * d / (sd * sd) + 2.f * logf(sd) + LOG2PI_F);
        }
    }

    // ---- block reductions ----
    __syncthreads();
    red[tid] = kl_acc; __syncthreads();
    for (int s2 = NTH / 2; s2 > 0; s2 >>= 1) {
        if (tid < s2) red[tid] += red[tid + s2];
        __syncthreads();
    }
    if (tid == 0) p.partials[blockIdx.x] = red[0];
    __syncthreads();
    red[tid] = nll_acc; __syncthreads();
    for (int s2 = NTH / 2; s2 > 0; s2 >>= 1) {
        if (tid < s2) red[tid] += red[tid + s2];
        __syncthreads();
    }
    if (tid == 0) p.partials[NWG + blockIdx.x] = red[0];
}

// ---------------- prep: pack weights into B-fragment order ----------------
struct PrepP {
    const float* eW1; const float* pW1; const float* dW1;
    const float* wih; const float* whh;
    const float* eW2; const float* pW2; const float* dW2;
    const float* hW[4];
    const float* dmW; const float* dsW;
    u16* dst;
};

__global__ void prep4(PrepP pp) {
    const int jNT[12]  = {8,8,8,24, 8,8,8, 1,1,1,1, 1};
    const int jKST[12] = {5,5,5,5, 4,4,4, 4,4,4,4, 4};
    const int jOFS[12] = {OF_E1,OF_P1,OF_D1,OF_G, OF_E2,OF_P2,OF_D2,
                          OF_H,OF_H+2048,OF_H+4096,OF_H+6144, OF_DH};
    const int jkt[3]   = {140,138,154};

    int job = blockIdx.y;
    int nt = jNT[job], kst = jKST[job];
    int per_agent = nt * kst * 512;
    int total = A_ * per_agent;
    int idx = blockIdx.x * 256 + threadIdx.x;
    if (idx >= total) return;
    int a = idx / per_agent;
    int rem = idx - a * per_agent;
    int slot = rem >> 9;            // /512
    int within = rem & 511;
    int lane = within >> 3, j = within & 7;
    int ntile = slot / kst, kstep = slot - ntile * kst;
    int k = kstep * 32 + (lane >> 4) * 8 + j;
    int n = ntile * 16 + (lane & 15);

    float val = 0.f;
    if (job < 3) {
        int sk = -1;
        if (job == 0)      sk = (k < 12) ? k : (k >= 32 ? k - 20 : -1);
        else if (job == 1) sk = (k >= 2 && k < 12) ? k - 2 : (k >= 32 ? k - 22 : -1);
        else               sk = (k >= 2 && k < 28) ? k - 2 : (k >= 32 ? k - 6 : -1);
        const float* s = (job == 0) ? pp.eW1 : (job == 1) ? pp.pW1 : pp.dW1;
        if (sk >= 0) val = s[((size_t)a * jkt[job] + sk) * 128 + n];
    } else if (job == 3) {
        if (k < 2)                  val = pp.wih[((size_t)a * 384 + n) * 18 + k];
        else if (k >= 12 && k < 28) val = pp.wih[((size_t)a * 384 + n) * 18 + (k - 10)];
        else if (k >= 32)           val = pp.whh[((size_t)a * 384 + n) * 128 + (k - 32)];
    } else if (job < 7) {
        const float* s = (job == 4) ? pp.eW2 : (job == 5) ? pp.pW2 : pp.dW2;
        val = s[((size_t)a * 128 + k) * 128 + n];
    } else if (job < 11) {
        val = pp.hW[job - 7][((size_t)a * 128 + k) * 16 + n];
    } else {
        if (n < 2)      val = pp.dmW[((size_t)a * 128 + k) * 2 + n];
        else if (n < 4) val = pp.dsW[((size_t)a * 128 + k) * 2 + (n - 2)];
    }
    pp.dst[(size_t)a * AGE + jOFS[job] + rem] = f2h(val);
}

__global__ void finish_kernel(const float* __restrict__ partials, float* __restrict__ out) {
    int tid = threadIdx.x;   // 64 threads
    float k = (tid < NWG) ? partials[tid] : 0.f;
    float n = (tid < NWG) ? partials[NWG + tid] : 0.f;
    k += __shfl_xor(k, 1);  n += __shfl_xor(n, 1);
    k += __shfl_xor(k, 2);  n += __shfl_xor(n, 2);
    k += __shfl_xor(k, 4);  n += __shfl_xor(n, 4);
    k += __shfl_xor(k, 8);  n += __shfl_xor(n, 8);
    k += __shfl_xor(k, 16); n += __shfl_xor(n, 16);
    k += __shfl_xor(k, 32); n += __shfl_xor(n, 32);
    if (tid == 0) { out[0] = k; out[1] = n; }
}

extern "C" void kernel_launch(void* const* d_in, const int* in_sizes, int n_in,
                              void* d_out, int out_size, void* d_ws, size_t ws_size,
                              hipStream_t stream) {
    float* partials = (float*)d_ws;                 // 80 floats
    u16* wq = (u16*)((char*)d_ws + 4096);           // packed frags, ~1.78 MB

    PrepP pp;
    pp.eW1 = (const float*)d_in[2];
    pp.pW1 = (const float*)d_in[10];
    pp.dW1 = (const float*)d_in[18];
    pp.wih = (const float*)d_in[26];
    pp.whh = (const float*)d_in[27];
    pp.eW2 = (const float*)d_in[4];
    pp.pW2 = (const float*)d_in[12];
    pp.dW2 = (const float*)d_in[20];
    pp.hW[0] = (const float*)d_in[6];   // emW
    pp.hW[1] = (const float*)d_in[8];   // esW
    pp.hW[2] = (const float*)d_in[14];  // pmW
    pp.hW[3] = (const float*)d_in[16];  // psW
    pp.dmW = (const float*)d_in[22];
    pp.dsW = (const float*)d_in[24];
    pp.dst = wq;
    // max job elems = 5 * 24*5*512 = 307200 -> 1200 blocks; y = 12 jobs
    prep4<<<dim3(1200, 12), 256, 0, stream>>>(pp);

    PM p;
    p.y   = (const float*)d_in[0];
    p.eps = (const float*)d_in[1];
    p.eb1 = (const float*)d_in[3];  p.eb2 = (const float*)d_in[5];
    p.emb = (const float*)d_in[7];  p.esb = (const float*)d_in[9];
    p.pb1 = (const float*)d_in[11]; p.pb2 = (const float*)d_in[13];
    p.pmb = (const float*)d_in[15]; p.psb = (const float*)d_in[17];
    p.db1 = (const float*)d_in[19]; p.db2 = (const float*)d_in[21];
    p.dmb = (const float*)d_in[23]; p.dsb = (const float*)d_in[25];
    p.bih = (const float*)d_in[28]; p.bhh = (const float*)d_in[29];
    p.wq = wq;
    p.partials = partials;

    vrnn10<<<NWG, NTH, 0, stream>>>(p);
    finish_kernel<<<1, 64, 0, stream>>>(partials, (float*)d_out);
}

// Round 11
// 891.468 us; speedup vs baseline: 1.7623x; 1.7623x over previous
//
#include <hip/hip_runtime.h>
#include <math.h>

typedef unsigned int u32;
typedef unsigned short u16;

#define NS 128          // T-1 timesteps
#define A_ 5
#define B_ 128
#define NTH 512
#define BC 16
#define NWG 40          // 5 agents x 8 chunks of 16 rows
#define LOG2PI_F 1.8378770664093453f

// ---- B-fragment packed weight layout (u16 units), per agent ----
// frag order: [layer][ntile][kstep][lane 0..63][j 0..7], elem = W[k][n] with
// k = kstep*32 + (lane>>4)*8 + j, n = ntile*16 + (lane&15).   (verified R10, absmax 0)
#define OF_E1 0         // 8 ntiles x 5 ksteps
#define OF_P1 20480
#define OF_D1 40960
#define OF_G  61440     // 24 ntiles x 5
#define OF_E2 122880    // 8 x 4
#define OF_P2 139264
#define OF_D2 155648
#define OF_H  172032    // 4 heads x (1 x 4)
#define OF_DH 180224    // 1 x 4 (cols: dm0 dm1 ds0 ds1, rest 0)
#define AGE   182272

typedef _Float16 f16x8 __attribute__((ext_vector_type(8)));
typedef float f32x4 __attribute__((ext_vector_type(4)));

__device__ __forceinline__ u16 f2h(float f) { _Float16 h = (_Float16)f; return __builtin_bit_cast(u16, h); }
__device__ __forceinline__ float h2f(u16 u) { return (float)__builtin_bit_cast(_Float16, u); }
__device__ __forceinline__ float softplusf_(float x) { return fmaxf(x, 0.f) + log1pf(expf(-fabsf(x))); }
__device__ __forceinline__ float sigmoidf_(float x) { return 1.f / (1.f + expf(-x)); }

#define MFMA16(af, bf, acc) __builtin_amdgcn_mfma_f32_16x16x32_f16((af), (bf), (acc), 0, 0, 0)

#define UST 168   // Uf row stride (elems)
#define AST 136   // activation row stride

struct PM {
    const float* __restrict__ y;
    const float* __restrict__ eps;
    const float* __restrict__ eb1; const float* __restrict__ eb2;
    const float* __restrict__ pb1; const float* __restrict__ pb2;
    const float* __restrict__ db1; const float* __restrict__ db2;
    const float* __restrict__ emb; const float* __restrict__ esb;
    const float* __restrict__ pmb; const float* __restrict__ psb;
    const float* __restrict__ dmb; const float* __restrict__ dsb;
    const float* __restrict__ bih; const float* __restrict__ bhh;
    const u16* __restrict__ wq;
    float* __restrict__ partials;
};

// 512 threads = 8 waves = 2 waves/SIMD (proven no-spill 128-VGPR point).
// GRU weights (120KB) LDS-resident; E1/P1/D1/E2/P2/D2/heads stream from L2.
__global__ void __launch_bounds__(NTH, 1) vrnn11(PM p) {
    const int tid = threadIdx.x;
    const int wave = tid >> 6;               // 0..7 = output tile group tg
    const int lane = tid & 63;
    const int ln = lane & 15;                // fragment row/col index
    const int lq = lane >> 4;                // k-quad / row-quad
    const int a = blockIdx.x >> 3;
    const int b0 = (blockIdx.x & 7) * BC;
    const int tg = wave;

    __shared__ __align__(16) u16 GL[61440];          // GRU B-frags, 120KB
    __shared__ __align__(16) u16 Uf[16 * UST];       // [x2 y10 z16 pad4 h128]
    __shared__ __align__(16) u16 aAf[16 * AST], aBf[16 * AST], aCf[16 * AST], aDf[16 * AST];
    __shared__ float mueL[16][17], sdeL[16][17], mupL[16][17], sdpL[16][17];
    __shared__ float xf[16][2], dmuL[16][2], dsdL[16][2];
    __shared__ float bE1L[128], bP1L[128], bD1L[128];
    __shared__ float bE2L[128], bP2L[128], bD2L[128];
    __shared__ float bIHL[384], bHHL[384], bHl[64], bDHl[4];
    __shared__ float redW[32];

    const f16x8* __restrict__ W8 = (const f16x8*)p.wq + (size_t)a * (AGE / 8);

    // ---- init: copy G to LDS (once), biases, zero U ----
    {
        const uint4* gsrc = (const uint4*)(p.wq + (size_t)a * AGE + OF_G);
        uint4* gdst = (uint4*)GL;
        for (int i = tid; i < 61440 / 8; i += NTH) gdst[i] = gsrc[i];
    }
    for (int i = tid; i < 16 * UST; i += NTH) Uf[i] = 0;
    if (tid < 128) {
        bE1L[tid] = p.eb1[a * 128 + tid]; bE2L[tid] = p.eb2[a * 128 + tid];
        bP1L[tid] = p.pb1[a * 128 + tid]; bP2L[tid] = p.pb2[a * 128 + tid];
        bD1L[tid] = p.db1[a * 128 + tid]; bD2L[tid] = p.db2[a * 128 + tid];
    }
    if (tid < 384) { bIHL[tid] = p.bih[a * 384 + tid]; bHHL[tid] = p.bhh[a * 384 + tid]; }
    if (tid < 64) {
        int h = tid >> 4, c = tid & 15;
        bHl[tid] = ((h == 0) ? p.emb : (h == 1) ? p.esb : (h == 2) ? p.pmb : p.psb)[a * 16 + c];
    }
    if (tid < 4) bDHl[tid] = (tid < 2) ? p.dmb[a * 2 + tid] : p.dsb[a * 2 + (tid - 2)];

    // ---- prefetch t=0 inputs ----
    const int ry = tid / 10, jy = tid - ry * 10;            // tid<160
    const int rx = (tid - 160) >> 1, xdx = (tid - 160) & 1; // 160<=tid<192
    const int re = tid >> 4, ze = tid & 15;                 // tid<256
    float ypre = 0.f, xpre = 0.f, epre = 0.f;
    if (tid < 160) ypre = p.y[0 * (B_ * 10) + (b0 + ry) * 10 + jy];
    else if (tid < 192) xpre = p.y[1 * (B_ * 10) + (b0 + rx) * 10 + a * 2 + xdx];
    if (tid < 256) epre = p.eps[(((size_t)0 * A_ + a) * B_ + (b0 + re)) * 16 + ze];

    float kl_acc = 0.f, nll_acc = 0.f;

#pragma unroll 1
    for (int t = 0; t < NS; ++t) {
        const int tn = (t + 1 < NS) ? t + 1 : t;
        __syncthreads();
        // ---- P1: commit inputs, prefetch next ----
        if (tid < 160) {
            Uf[ry * UST + 2 + jy] = f2h(ypre);
            ypre = p.y[tn * (B_ * 10) + (b0 + ry) * 10 + jy];
        } else if (tid < 192) {
            Uf[rx * UST + xdx] = f2h(xpre); xf[rx][xdx] = xpre;
            xpre = p.y[(tn + 1) * (B_ * 10) + (b0 + rx) * 10 + a * 2 + xdx];
        }
        __syncthreads();

        // ---- P2: enc1 + pri1  (1 tile each per wave, B from L2) ----
        {
            f32x4 accE = {0,0,0,0}, accP = {0,0,0,0};
#pragma unroll
            for (int k = 0; k < 5; ++k) {
                f16x8 af = *(const f16x8*)(Uf + ln * UST + k * 32 + lq * 8);
                f16x8 b1 = W8[OF_E1 / 8 + (tg * 5 + k) * 64 + lane];
                accE = MFMA16(af, b1, accE);
                f16x8 b2 = W8[OF_P1 / 8 + (tg * 5 + k) * 64 + lane];
                accP = MFMA16(af, b2, accP);
            }
            int c = tg * 16 + ln;
            float bE = bE1L[c], bP = bP1L[c];
#pragma unroll
            for (int j = 0; j < 4; ++j) {
                int row = lq * 4 + j;
                aAf[row * AST + c] = f2h(fmaxf(accE[j] + bE, 0.f));
                aCf[row * AST + c] = f2h(fmaxf(accP[j] + bP, 0.f));
            }
        }
        __syncthreads();

        // ---- P3: enc2 (aAf->aBf), pri2 (aCf->aDf), B from L2 ----
        {
            f32x4 accE = {0,0,0,0}, accP = {0,0,0,0};
#pragma unroll
            for (int k = 0; k < 4; ++k) {
                f16x8 a1 = *(const f16x8*)(aAf + ln * AST + k * 32 + lq * 8);
                f16x8 a2 = *(const f16x8*)(aCf + ln * AST + k * 32 + lq * 8);
                f16x8 b1 = W8[OF_E2 / 8 + (tg * 4 + k) * 64 + lane];
                accE = MFMA16(a1, b1, accE);
                f16x8 b2 = W8[OF_P2 / 8 + (tg * 4 + k) * 64 + lane];
                accP = MFMA16(a2, b2, accP);
            }
            int c = tg * 16 + ln;
            float bE = bE2L[c], bP = bP2L[c];
#pragma unroll
            for (int j = 0; j < 4; ++j) {
                int row = lq * 4 + j;
                aBf[row * AST + c] = f2h(fmaxf(accE[j] + bE, 0.f));
                aDf[row * AST + c] = f2h(fmaxf(accP[j] + bP, 0.f));
            }
        }
        __syncthreads();

        // ---- P4: 4 gaussian heads (waves 0-3; B from L2) ----
        if (wave < 4) {
            const u16* src = (wave < 2) ? aBf : aDf;
            f32x4 acc = {0,0,0,0};
#pragma unroll
            for (int k = 0; k < 4; ++k) {
                f16x8 af = *(const f16x8*)(src + ln * AST + k * 32 + lq * 8);
                f16x8 bf = W8[OF_H / 8 + wave * 256 + k * 64 + lane];
                acc = MFMA16(af, bf, acc);
            }
            float bb = bHl[wave * 16 + ln];
#pragma unroll
            for (int j = 0; j < 4; ++j) {
                int row = lq * 4 + j;
                float v = acc[j] + bb;
                if (wave == 0)      mueL[row][ln] = v;
                else if (wave == 1) sdeL[row][ln] = softplusf_(v);
                else if (wave == 2) mupL[row][ln] = v;
                else                sdpL[row][ln] = softplusf_(v);
            }
        }
        __syncthreads();

        // ---- P5: z sample + KL (256 threads) ----
        if (tid < 256) {
            float em = mueL[re][ze], es = sdeL[re][ze], pm = mupL[re][ze], ps = sdpL[re][ze];
            float zv = fmaf(epre, es, em);
            Uf[re * UST + 12 + ze] = f2h(zv);
            float dm = em - pm;
            kl_acc += 0.5f * (2.f * (logf(ps) - logf(es)) + (es * es + dm * dm) / (ps * ps) - 1.f);
            epre = p.eps[(((size_t)tn * A_ + a) * B_ + (b0 + re)) * 16 + ze];
        }
        __syncthreads();

        // ---- P6: dec1 (L2) + GRU gates (LDS); wave owns col group tg ----
        float hn[4];
        {
            f32x4 aO = {0,0,0,0}, g0 = {0,0,0,0}, g1 = {0,0,0,0};
            f32x4 g2i = {0,0,0,0}, g2h = {0,0,0,0};
#pragma unroll
            for (int k = 0; k < 5; ++k) {
                f16x8 af = *(const f16x8*)(Uf + ln * UST + k * 32 + lq * 8);
                f16x8 bD = W8[OF_D1 / 8 + (tg * 5 + k) * 64 + lane];
                aO = MFMA16(af, bD, aO);
                f16x8 b0 = *(const f16x8*)(GL + ((0 + tg) * 5 + k) * 512 + lane * 8);
                g0 = MFMA16(af, b0, g0);
                f16x8 b1 = *(const f16x8*)(GL + ((8 + tg) * 5 + k) * 512 + lane * 8);
                g1 = MFMA16(af, b1, g1);
                f16x8 b2 = *(const f16x8*)(GL + ((16 + tg) * 5 + k) * 512 + lane * 8);
                if (k == 0) g2i = MFMA16(af, b2, g2i);
                else        g2h = MFMA16(af, b2, g2h);
            }
            int c = tg * 16 + ln;
            float bD = bD1L[c];
            float br = bIHL[c] + bHHL[c];
            float bz = bIHL[128 + c] + bHHL[128 + c];
            float bgi = bIHL[256 + c], bgh = bHHL[256 + c];
#pragma unroll
            for (int j = 0; j < 4; ++j) {
                int row = lq * 4 + j;
                aAf[row * AST + c] = f2h(fmaxf(aO[j] + bD, 0.f));
                float rr = sigmoidf_(g0[j] + br);
                float zz = sigmoidf_(g1[j] + bz);
                float nn = tanhf(fmaf(rr, g2h[j] + bgh, g2i[j] + bgi));
                float hold = h2f(Uf[row * UST + 32 + c]);
                hn[j] = fmaf(zz, hold - nn, nn);
            }
        }
        __syncthreads();

        // ---- P7: h write + dec2 (aAf -> aBf, B from L2) ----
        {
            int c = tg * 16 + ln;
#pragma unroll
            for (int j = 0; j < 4; ++j)
                Uf[(lq * 4 + j) * UST + 32 + c] = f2h(hn[j]);
            f32x4 acc = {0,0,0,0};
#pragma unroll
            for (int k = 0; k < 4; ++k) {
                f16x8 af = *(const f16x8*)(aAf + ln * AST + k * 32 + lq * 8);
                f16x8 bf = W8[OF_D2 / 8 + (tg * 4 + k) * 64 + lane];
                acc = MFMA16(af, bf, acc);
            }
            float bE = bD2L[c];
#pragma unroll
            for (int j = 0; j < 4; ++j)
                aBf[(lq * 4 + j) * AST + c] = f2h(fmaxf(acc[j] + bE, 0.f));
        }
        __syncthreads();

        // ---- P8: dec heads (wave 0): [16x128]x[128x4] ----
        if (wave == 0) {
            f32x4 acc = {0,0,0,0};
#pragma unroll
            for (int k = 0; k < 4; ++k) {
                f16x8 af = *(const f16x8*)(aBf + ln * AST + k * 32 + lq * 8);
                f16x8 bf = W8[OF_DH / 8 + k * 64 + lane];
                acc = MFMA16(af, bf, acc);
            }
            if (ln < 4) {
                float bb = bDHl[ln];
#pragma unroll
                for (int j = 0; j < 4; ++j) {
                    int row = lq * 4 + j;
                    float v = acc[j] + bb;
                    if (ln < 2) dmuL[row][ln] = v;
                    else        dsdL[row][ln - 2] = softplusf_(v);
                }
            }
        }
        __syncthreads();

        // ---- P9: NLL (16 rows x 2 dims) ----
        if (tid < 32) {
            int r = tid >> 1, xd = tid & 1;
            float d = xf[r][xd] - dmuL[r][xd];
            float sd = dsdL[r][xd];
            nll_acc += 0.5f * (d * d / (sd * sd) + 2.f * logf(sd) + LOG2PI_F);
        }
    }

    // ---- block reduction (shuffle per wave, tiny serial finish) ----
    __syncthreads();
    {
        float k = kl_acc, n = nll_acc;
        k += __shfl_xor(k, 1);  n += __shfl_xor(n, 1);
        k += __shfl_xor(k, 2);  n += __shfl_xor(n, 2);
        k += __shfl_xor(k, 4);  n += __shfl_xor(n, 4);
        k += __shfl_xor(k, 8);  n += __shfl_xor(n, 8);
        k += __shfl_xor(k, 16); n += __shfl_xor(n, 16);
        k += __shfl_xor(k, 32); n += __shfl_xor(n, 32);
        if (lane == 0) { redW[wave] = k; redW[16 + wave] = n; }
    }
    __syncthreads();
    if (tid == 0) {
        float s = 0.f, s2 = 0.f;
#pragma unroll
        for (int i = 0; i < 8; ++i) { s += redW[i]; s2 += redW[16 + i]; }
        p.partials[blockIdx.x] = s;
        p.partials[NWG + blockIdx.x] = s2;
    }
}

// ---------------- prep: pack weights into B-fragment order ----------------
struct PrepP {
    const float* eW1; const float* pW1; const float* dW1;
    const float* wih; const float* whh;
    const float* eW2; const float* pW2; const float* dW2;
    const float* hW[4];
    const float* dmW; const float* dsW;
    u16* dst;
};

__global__ void prep4(PrepP pp) {
    const int jNT[12]  = {8,8,8,24, 8,8,8, 1,1,1,1, 1};
    const int jKST[12] = {5,5,5,5, 4,4,4, 4,4,4,4, 4};
    const int jOFS[12] = {OF_E1,OF_P1,OF_D1,OF_G, OF_E2,OF_P2,OF_D2,
                          OF_H,OF_H+2048,OF_H+4096,OF_H+6144, OF_DH};
    const int jkt[3]   = {140,138,154};

    int job = blockIdx.y;
    int nt = jNT[job], kst = jKST[job];
    int per_agent = nt * kst * 512;
    int total = A_ * per_agent;
    int idx = blockIdx.x * 256 + threadIdx.x;
    if (idx >= total) return;
    int a = idx / per_agent;
    int rem = idx - a * per_agent;
    int slot = rem >> 9;            // /512
    int within = rem & 511;
    int lane = within >> 3, j = within & 7;
    int ntile = slot / kst, kstep = slot - ntile * kst;
    int k = kstep * 32 + (lane >> 4) * 8 + j;
    int n = ntile * 16 + (lane & 15);

    float val = 0.f;
    if (job < 3) {
        int sk = -1;
        if (job == 0)      sk = (k < 12) ? k : (k >= 32 ? k - 20 : -1);
        else if (job == 1) sk = (k >= 2 && k < 12) ? k - 2 : (k >= 32 ? k - 22 : -1);
        else               sk = (k >= 2 && k < 28) ? k - 2 : (k >= 32 ? k - 6 : -1);
        const float* s = (job == 0) ? pp.eW1 : (job == 1) ? pp.pW1 : pp.dW1;
        if (sk >= 0) val = s[((size_t)a * jkt[job] + sk) * 128 + n];
    } else if (job == 3) {
        if (k < 2)                  val = pp.wih[((size_t)a * 384 + n) * 18 + k];
        else if (k >= 12 && k < 28) val = pp.wih[((size_t)a * 384 + n) * 18 + (k - 10)];
        else if (k >= 32)           val = pp.whh[((size_t)a * 384 + n) * 128 + (k - 32)];
    } else if (job < 7) {
        const float* s = (job == 4) ? pp.eW2 : (job == 5) ? pp.pW2 : pp.dW2;
        val = s[((size_t)a * 128 + k) * 128 + n];
    } else if (job < 11) {
        val = pp.hW[job - 7][((size_t)a * 128 + k) * 16 + n];
    } else {
        if (n < 2)      val = pp.dmW[((size_t)a * 128 + k) * 2 + n];
        else if (n < 4) val = pp.dsW[((size_t)a * 128 + k) * 2 + (n - 2)];
    }
    pp.dst[(size_t)a * AGE + jOFS[job] + rem] = f2h(val);
}

__global__ void finish_kernel(const float* __restrict__ partials, float* __restrict__ out) {
    int tid = threadIdx.x;   // 64 threads
    float k = (tid < NWG) ? partials[tid] : 0.f;
    float n = (tid < NWG) ? partials[NWG + tid] : 0.f;
    k += __shfl_xor(k, 1);  n += __shfl_xor(n, 1);
    k += __shfl_xor(k, 2);  n += __shfl_xor(n, 2);
    k += __shfl_xor(k, 4);  n += __shfl_xor(n, 4);
    k += __shfl_xor(k, 8);  n += __shfl_xor(n, 8);
    k += __shfl_xor(k, 16); n += __shfl_xor(n, 16);
    k += __shfl_xor(k, 32); n += __shfl_xor(n, 32);
    if (tid == 0) { out[0] = k; out[1] = n; }
}

extern "C" void kernel_launch(void* const* d_in, const int* in_sizes, int n_in,
                              void* d_out, int out_size, void* d_ws, size_t ws_size,
                              hipStream_t stream) {
    float* partials = (float*)d_ws;                 // 80 floats
    u16* wq = (u16*)((char*)d_ws + 4096);           // packed frags, ~1.78 MB

    PrepP pp;
    pp.eW1 = (const float*)d_in[2];
    pp.pW1 = (const float*)d_in[10];
    pp.dW1 = (const float*)d_in[18];
    pp.wih = (const float*)d_in[26];
    pp.whh = (const float*)d_in[27];
    pp.eW2 = (const float*)d_in[4];
    pp.pW2 = (const float*)d_in[12];
    pp.dW2 = (const float*)d_in[20];
    pp.hW[0] = (const float*)d_in[6];   // emW
    pp.hW[1] = (const float*)d_in[8];   // esW
    pp.hW[2] = (const float*)d_in[14];  // pmW
    pp.hW[3] = (const float*)d_in[16];  // psW
    pp.dmW = (const float*)d_in[22];
    pp.dsW = (const float*)d_in[24];
    pp.dst = wq;
    // max job elems = 5 * 24*5*512 = 307200 -> 1200 blocks; y = 12 jobs
    prep4<<<dim3(1200, 12), 256, 0, stream>>>(pp);

    PM p;
    p.y   = (const float*)d_in[0];
    p.eps = (const float*)d_in[1];
    p.eb1 = (const float*)d_in[3];  p.eb2 = (const float*)d_in[5];
    p.emb = (const float*)d_in[7];  p.esb = (const float*)d_in[9];
    p.pb1 = (const float*)d_in[11]; p.pb2 = (const float*)d_in[13];
    p.pmb = (const float*)d_in[15]; p.psb = (const float*)d_in[17];
    p.db1 = (const float*)d_in[19]; p.db2 = (const float*)d_in[21];
    p.dmb = (const float*)d_in[23]; p.dsb = (const float*)d_in[25];
    p.bih = (const float*)d_in[28]; p.bhh = (const float*)d_in[29];
    p.wq = wq;
    p.partials = partials;

    vrnn11<<<NWG, NTH, 0, stream>>>(p);
    finish_kernel<<<1, 64, 0, stream>>>(partials, (float*)d_out);
}